// Round 2
// baseline (278.296 us; speedup 1.0000x reference)
//
#include <hip/hip_runtime.h>

#define HH 4096
#define WW 4096
#define KK 256
#define RMAX 10
#define DD (2 * RMAX + 1)          // 21
#define MAXTOUCH (KK * DD * DD)    // 112896

// d_ws layout:
//   [0]  double sf     (sum field^2)
//   [8]  double su     (sum fu^2)
//   [16] uint   count  (compact list counter)
//   [32] int    list_idx[MAXTOUCH]
//   [32 + 4*MAXTOUCH] float list_fu[MAXTOUCH]
#define WS_IDX_OFF 32
#define WS_FU_OFF  (32 + 4 * MAXTOUCH)

// K0: clear the 21x21 in-bounds square of every attractor in the addmap
// (addmap lives in d_out; it is consumed before the blend overwrites d_out).
__global__ void ecli_clear(const int* __restrict__ pos, float* __restrict__ addmap) {
    const int k = blockIdx.x;
    const int t = threadIdx.x;
    if (t >= DD * DD) return;
    const int ni = pos[2 * k + 0] + t / DD - RMAX;
    const int nj = pos[2 * k + 1] + t % DD - RMAX;
    if (ni < 0 || ni >= HH || nj < 0 || nj >= WW) return;
    addmap[(size_t)ni * WW + nj] = 0.0f;
}

// K1: scatter-add attractor contributions into addmap.
__global__ void ecli_scatter(const int* __restrict__ pos,
                             const float* __restrict__ strength,
                             const float* __restrict__ local_ratio,
                             float* __restrict__ addmap) {
    const int k = blockIdx.x;
    const int t = threadIdx.x;
    if (t >= DD * DD) return;
    const float s   = strength[k];
    const float lr  = *local_ratio;
    const float rad = floorf(5.0f * s);
    const float inv = -0.5f / (4.0f * s * s);
    const float amp = lr * s;
    const int di = t / DD - RMAX;
    const int dj = t % DD - RMAX;
    if (fabsf((float)di) > rad || fabsf((float)dj) > rad) return;
    const int ni = pos[2 * k + 0] + di;
    const int nj = pos[2 * k + 1] + dj;
    if (ni < 0 || ni >= HH || nj < 0 || nj >= WW) return;
    const float c = expf((float)(di * di + dj * dj) * inv) * amp;
    atomicAdd(&addmap[(size_t)ni * WW + nj], c);
}

// K2: claim each touched pixel once (atomicExch -> 0), compute corrected fu1,
// append (idx, fu1) to compact list, and correct the fu^2 norm sum.
__global__ void ecli_fixup(const int* __restrict__ pos,
                           const float* __restrict__ field,
                           const float* __restrict__ signal,
                           const float* __restrict__ gratio,
                           const float* __restrict__ infl,
                           float* __restrict__ addmap,
                           double* __restrict__ norms,
                           unsigned int* __restrict__ count,
                           int* __restrict__ list_idx,
                           float* __restrict__ list_fu) {
    const int k = blockIdx.x;
    const int t = threadIdx.x;
    if (t >= DD * DD) return;
    const int ni = pos[2 * k + 0] + t / DD - RMAX;
    const int nj = pos[2 * k + 1] + t % DD - RMAX;
    if (ni < 0 || ni >= HH || nj < 0 || nj >= WW) return;
    const size_t idx = (size_t)ni * WW + nj;
    const float val = atomicExch(&addmap[idx], 0.0f);
    if (val == 0.0f) return;                 // nothing accumulated, or already claimed
    const float gr = *gratio;
    const float is = *infl;
    const float f = field[idx];
    const float g = signal[idx];
    const float m0 = is / (1.0f + expf(-gr));
    const float m1 = is / (1.0f + expf(-(gr + val)));
    const float fu0 = fmaf(g - f, m0, f);    // what the uniform blend will write
    const float fu1 = fmaf(g - f, m1, f);    // corrected value
    const unsigned int p = atomicAdd(count, 1u);
    list_idx[p] = (int)idx;
    list_fu[p]  = fu1;
    atomicAdd(&norms[1], (double)fu1 * (double)fu1 - (double)fu0 * (double)fu0);
}

// K3: uniform blend (m is constant), unrolled 2x4 float4 for MLP; norm accum.
__global__ void __launch_bounds__(256) ecli_blend(
        const float* __restrict__ field,
        const float* __restrict__ signal,
        const float* __restrict__ gratio,
        const float* __restrict__ infl,
        float* __restrict__ out,
        double* __restrict__ norms) {
    const int tid    = blockIdx.x * 256 + threadIdx.x;
    const int stride = 2048 * 256;
    const float gr = *gratio;
    const float is = *infl;
    const float m0 = is / (1.0f + expf(-gr));
    double sf = 0.0, su = 0.0;
    const float4* F = (const float4*)field;
    const float4* G = (const float4*)signal;
    float4*       O = (float4*)out;
    #pragma unroll
    for (int c = 0; c < 2; ++c) {
        const int i0 = tid + (4 * c + 0) * stride;
        const int i1 = tid + (4 * c + 1) * stride;
        const int i2 = tid + (4 * c + 2) * stride;
        const int i3 = tid + (4 * c + 3) * stride;
        float4 f0 = F[i0], f1 = F[i1], f2 = F[i2], f3 = F[i3];
        float4 g0 = G[i0], g1 = G[i1], g2 = G[i2], g3 = G[i3];
        float4 r0, r1, r2, r3;
        r0.x = fmaf(g0.x - f0.x, m0, f0.x); r0.y = fmaf(g0.y - f0.y, m0, f0.y);
        r0.z = fmaf(g0.z - f0.z, m0, f0.z); r0.w = fmaf(g0.w - f0.w, m0, f0.w);
        r1.x = fmaf(g1.x - f1.x, m0, f1.x); r1.y = fmaf(g1.y - f1.y, m0, f1.y);
        r1.z = fmaf(g1.z - f1.z, m0, f1.z); r1.w = fmaf(g1.w - f1.w, m0, f1.w);
        r2.x = fmaf(g2.x - f2.x, m0, f2.x); r2.y = fmaf(g2.y - f2.y, m0, f2.y);
        r2.z = fmaf(g2.z - f2.z, m0, f2.z); r2.w = fmaf(g2.w - f2.w, m0, f2.w);
        r3.x = fmaf(g3.x - f3.x, m0, f3.x); r3.y = fmaf(g3.y - f3.y, m0, f3.y);
        r3.z = fmaf(g3.z - f3.z, m0, f3.z); r3.w = fmaf(g3.w - f3.w, m0, f3.w);
        O[i0] = r0; O[i1] = r1; O[i2] = r2; O[i3] = r3;
        sf += (double)f0.x*f0.x + (double)f0.y*f0.y + (double)f0.z*f0.z + (double)f0.w*f0.w
            + (double)f1.x*f1.x + (double)f1.y*f1.y + (double)f1.z*f1.z + (double)f1.w*f1.w;
        sf += (double)f2.x*f2.x + (double)f2.y*f2.y + (double)f2.z*f2.z + (double)f2.w*f2.w
            + (double)f3.x*f3.x + (double)f3.y*f3.y + (double)f3.z*f3.z + (double)f3.w*f3.w;
        su += (double)r0.x*r0.x + (double)r0.y*r0.y + (double)r0.z*r0.z + (double)r0.w*r0.w
            + (double)r1.x*r1.x + (double)r1.y*r1.y + (double)r1.z*r1.z + (double)r1.w*r1.w;
        su += (double)r2.x*r2.x + (double)r2.y*r2.y + (double)r2.z*r2.z + (double)r2.w*r2.w
            + (double)r3.x*r3.x + (double)r3.y*r3.y + (double)r3.z*r3.z + (double)r3.w*r3.w;
    }
    #pragma unroll
    for (int off = 32; off > 0; off >>= 1) {
        sf += __shfl_down(sf, off);
        su += __shfl_down(su, off);
    }
    if ((threadIdx.x & 63) == 0) {
        atomicAdd(&norms[0], sf);
        atomicAdd(&norms[1], su);
    }
}

// K4: apply sparse corrections (pre-scale values).
__global__ void ecli_apply(const unsigned int* __restrict__ count,
                           const int* __restrict__ list_idx,
                           const float* __restrict__ list_fu,
                           float* __restrict__ out) {
    const unsigned int n = *count;
    const unsigned int tid = blockIdx.x * blockDim.x + threadIdx.x;
    if (tid < n) out[list_idx[tid]] = list_fu[tid];
}

// K5: out *= ||field|| / ||fu||, unrolled for MLP.
__global__ void __launch_bounds__(256) ecli_scale(
        float* __restrict__ out, const double* __restrict__ norms) {
    const double nf = norms[0];
    const double nu = norms[1];
    const float scale = (nu > 0.0) ? (float)sqrt(nf / nu) : 1.0f;
    const int tid    = blockIdx.x * 256 + threadIdx.x;
    const int stride = 2048 * 256;
    float4* O = (float4*)out;
    #pragma unroll
    for (int c = 0; c < 2; ++c) {
        const int i0 = tid + (4 * c + 0) * stride;
        const int i1 = tid + (4 * c + 1) * stride;
        const int i2 = tid + (4 * c + 2) * stride;
        const int i3 = tid + (4 * c + 3) * stride;
        float4 v0 = O[i0], v1 = O[i1], v2 = O[i2], v3 = O[i3];
        v0.x *= scale; v0.y *= scale; v0.z *= scale; v0.w *= scale;
        v1.x *= scale; v1.y *= scale; v1.z *= scale; v1.w *= scale;
        v2.x *= scale; v2.y *= scale; v2.z *= scale; v2.w *= scale;
        v3.x *= scale; v3.y *= scale; v3.z *= scale; v3.w *= scale;
        O[i0] = v0; O[i1] = v1; O[i2] = v2; O[i3] = v3;
    }
}

extern "C" void kernel_launch(void* const* d_in, const int* in_sizes, int n_in,
                              void* d_out, int out_size, void* d_ws, size_t ws_size,
                              hipStream_t stream) {
    const float* field    = (const float*)d_in[0];
    const float* signal   = (const float*)d_in[1];
    const int*   pos      = (const int*)d_in[2];
    const float* strength = (const float*)d_in[3];
    const float* infl     = (const float*)d_in[4];
    const float* gratio   = (const float*)d_in[5];
    const float* lratio   = (const float*)d_in[6];
    float* out = (float*)d_out;

    char* ws = (char*)d_ws;
    double*       norms    = (double*)ws;
    unsigned int* count    = (unsigned int*)(ws + 16);
    int*          list_idx = (int*)(ws + WS_IDX_OFF);
    float*        list_fu  = (float*)(ws + WS_FU_OFF);

    // zero norms + counter (32 bytes)
    hipMemsetAsync(d_ws, 0, 32, stream);

    ecli_clear  <<<KK, 448, 0, stream>>>(pos, out);
    ecli_scatter<<<KK, 448, 0, stream>>>(pos, strength, lratio, out);
    ecli_fixup  <<<KK, 448, 0, stream>>>(pos, field, signal, gratio, infl,
                                         out, norms, count, list_idx, list_fu);
    ecli_blend  <<<2048, 256, 0, stream>>>(field, signal, gratio, infl, out, norms);
    ecli_apply  <<<(MAXTOUCH + 255) / 256, 256, 0, stream>>>(count, list_idx, list_fu, out);
    ecli_scale  <<<2048, 256, 0, stream>>>(out, norms);
}

// Round 4
// 74.579 us; speedup vs baseline: 3.7316x; 3.7316x over previous
//
#include <hip/hip_runtime.h>

#define HH 4096
#define WW 4096
#define KK 256
#define RMAX 10
#define DD 21
#define NSQ (DD * DD)              // 441
#define MAXTOUCH (KK * NSQ)        // 112896

#define GRID 2048
#define TPB 256
#define STRIDE (GRID * TPB)        // float4 units = 524288
#define ITER 8                     // (HH*WW/4) / STRIDE

// d_ws layout (bytes):
#define FIX_OFF   0                      // double fix_delta[KK]      (2048 B)
#define PSF_OFF   4096                   // double part_sf[GRID]      (16384 B)
#define PSU_OFF   20480                  // double part_su[GRID]      (16384 B)
#define SCALE_OFF 36864                  // float  scale
#define LIDX_OFF  40960                  // int    list_idx[MAXTOUCH] (451584 B)
#define LFU_OFF   (40960 + 451584)       // float  list_fu[MAXTOUCH]

// K0: zero the 21x21 in-bounds square of every attractor in the addmap.
// addmap lives in d_out (holds stale output during timed replays).
__global__ void ecli_clear(const int* __restrict__ pos, float* __restrict__ addmap) {
    const int k = blockIdx.x;
    const int t = threadIdx.x;
    if (t >= NSQ) return;
    const int ni = pos[2 * k + 0] + t / DD - RMAX;
    const int nj = pos[2 * k + 1] + t % DD - RMAX;
    if (ni < 0 || ni >= HH || nj < 0 || nj >= WW) return;
    addmap[(size_t)ni * WW + nj] = 0.0f;
}

// K1: scatter-add attractor contributions (f32 atomics, essentially uncontended).
__global__ void ecli_scatter(const int* __restrict__ pos,
                             const float* __restrict__ strength,
                             const float* __restrict__ local_ratio,
                             float* __restrict__ addmap) {
    const int k = blockIdx.x;
    const int t = threadIdx.x;
    if (t >= NSQ) return;
    const float s   = strength[k];
    const float lr  = *local_ratio;
    const float rad = floorf(5.0f * s);
    const float inv = -0.5f / (4.0f * s * s);
    const float amp = lr * s;
    const int di = t / DD - RMAX;
    const int dj = t % DD - RMAX;
    if (fabsf((float)di) > rad || fabsf((float)dj) > rad) return;
    const int ni = pos[2 * k + 0] + di;
    const int nj = pos[2 * k + 1] + dj;
    if (ni < 0 || ni >= HH || nj < 0 || nj >= WW) return;
    const float c = expf((float)(di * di + dj * dj) * inv) * amp;
    atomicAdd(&addmap[(size_t)ni * WW + nj], c);
}

// K2: claim each touched pixel once (atomicExch->0, distinct addrs), write
// (idx, fu1) into deterministic slot k*441+t (or -1), block-reduce the
// su-correction into fix_delta[k]. No contended atomics, no list memset.
__global__ void ecli_fixup(const int* __restrict__ pos,
                           const float* __restrict__ field,
                           const float* __restrict__ signal,
                           const float* __restrict__ gratio,
                           const float* __restrict__ infl,
                           float* __restrict__ addmap,
                           int* __restrict__ list_idx,
                           float* __restrict__ list_fu,
                           double* __restrict__ fix_delta) {
    const int k = blockIdx.x;
    const int t = threadIdx.x;
    double delta = 0.0;
    if (t < NSQ) {
        int out_idx = -1;
        float out_fu = 0.0f;
        const int ni = pos[2 * k + 0] + t / DD - RMAX;
        const int nj = pos[2 * k + 1] + t % DD - RMAX;
        if (ni >= 0 && ni < HH && nj >= 0 && nj < WW) {
            const size_t idx = (size_t)ni * WW + nj;
            const float val = atomicExch(&addmap[idx], 0.0f);
            if (val != 0.0f) {
                const float gr = *gratio;
                const float is = *infl;
                const float f = field[idx];
                const float g = signal[idx];
                const float m0 = is / (1.0f + expf(-gr));
                const float m1 = is / (1.0f + expf(-(gr + val)));
                const float fu0 = fmaf(g - f, m0, f);
                const float fu1 = fmaf(g - f, m1, f);
                out_idx = (int)idx;
                out_fu  = fu1;
                delta = (double)fu1 * (double)fu1 - (double)fu0 * (double)fu0;
            }
        }
        list_idx[k * NSQ + t] = out_idx;
        list_fu [k * NSQ + t] = out_fu;
    }
    __shared__ double sred[7];
    #pragma unroll
    for (int off = 32; off > 0; off >>= 1) delta += __shfl_down(delta, off);
    if ((t & 63) == 0) sred[t >> 6] = delta;
    __syncthreads();
    if (t == 0) {
        double d = 0.0;
        #pragma unroll
        for (int i = 0; i < 7; ++i) d += sred[i];
        fix_delta[k] = d;
    }
}

// K3: uniform blend, write unscaled fu, per-block partial norms (plain stores).
__global__ void __launch_bounds__(TPB) ecli_blend(
        const float* __restrict__ field,
        const float* __restrict__ signal,
        const float* __restrict__ gratio,
        const float* __restrict__ infl,
        float* __restrict__ out,
        double* __restrict__ part_sf,
        double* __restrict__ part_su) {
    const int tid = blockIdx.x * TPB + threadIdx.x;
    const float gr = *gratio;
    const float is = *infl;
    const float m0 = is / (1.0f + expf(-gr));
    const float4* __restrict__ F = (const float4*)field;
    const float4* __restrict__ G = (const float4*)signal;
    float4* __restrict__ O = (float4*)out;
    double sf = 0.0, su = 0.0;
    #pragma unroll
    for (int u = 0; u < ITER / 4; ++u) {
        const int i0 = tid + (4 * u + 0) * STRIDE;
        const int i1 = tid + (4 * u + 1) * STRIDE;
        const int i2 = tid + (4 * u + 2) * STRIDE;
        const int i3 = tid + (4 * u + 3) * STRIDE;
        float4 f0 = F[i0], f1 = F[i1], f2 = F[i2], f3 = F[i3];
        float4 g0 = G[i0], g1 = G[i1], g2 = G[i2], g3 = G[i3];
        float4 r0, r1, r2, r3;
        r0.x = fmaf(g0.x - f0.x, m0, f0.x); r0.y = fmaf(g0.y - f0.y, m0, f0.y);
        r0.z = fmaf(g0.z - f0.z, m0, f0.z); r0.w = fmaf(g0.w - f0.w, m0, f0.w);
        r1.x = fmaf(g1.x - f1.x, m0, f1.x); r1.y = fmaf(g1.y - f1.y, m0, f1.y);
        r1.z = fmaf(g1.z - f1.z, m0, f1.z); r1.w = fmaf(g1.w - f1.w, m0, f1.w);
        r2.x = fmaf(g2.x - f2.x, m0, f2.x); r2.y = fmaf(g2.y - f2.y, m0, f2.y);
        r2.z = fmaf(g2.z - f2.z, m0, f2.z); r2.w = fmaf(g2.w - f2.w, m0, f2.w);
        r3.x = fmaf(g3.x - f3.x, m0, f3.x); r3.y = fmaf(g3.y - f3.y, m0, f3.y);
        r3.z = fmaf(g3.z - f3.z, m0, f3.z); r3.w = fmaf(g3.w - f3.w, m0, f3.w);
        O[i0] = r0; O[i1] = r1; O[i2] = r2; O[i3] = r3;
        sf += (double)f0.x*f0.x + (double)f0.y*f0.y + (double)f0.z*f0.z + (double)f0.w*f0.w
            + (double)f1.x*f1.x + (double)f1.y*f1.y + (double)f1.z*f1.z + (double)f1.w*f1.w
            + (double)f2.x*f2.x + (double)f2.y*f2.y + (double)f2.z*f2.z + (double)f2.w*f2.w
            + (double)f3.x*f3.x + (double)f3.y*f3.y + (double)f3.z*f3.z + (double)f3.w*f3.w;
        su += (double)r0.x*r0.x + (double)r0.y*r0.y + (double)r0.z*r0.z + (double)r0.w*r0.w
            + (double)r1.x*r1.x + (double)r1.y*r1.y + (double)r1.z*r1.z + (double)r1.w*r1.w
            + (double)r2.x*r2.x + (double)r2.y*r2.y + (double)r2.z*r2.z + (double)r2.w*r2.w
            + (double)r3.x*r3.x + (double)r3.y*r3.y + (double)r3.z*r3.z + (double)r3.w*r3.w;
    }
    __shared__ double sred[8];
    #pragma unroll
    for (int off = 32; off > 0; off >>= 1) {
        sf += __shfl_down(sf, off);
        su += __shfl_down(su, off);
    }
    if ((threadIdx.x & 63) == 0) {
        sred[(threadIdx.x >> 6) * 2 + 0] = sf;
        sred[(threadIdx.x >> 6) * 2 + 1] = su;
    }
    __syncthreads();
    if (threadIdx.x == 0) {
        part_sf[blockIdx.x] = sred[0] + sred[2] + sred[4] + sred[6];
        part_su[blockIdx.x] = sred[1] + sred[3] + sred[5] + sred[7];
    }
}

// K4: every block redundantly reduces partials (L2-resident) -> scale,
// then rescales its slice of out in place.
__global__ void __launch_bounds__(TPB) ecli_scale(
        float* __restrict__ out,
        const double* __restrict__ part_sf,
        const double* __restrict__ part_su,
        const double* __restrict__ fix_delta,
        float* __restrict__ scale_out) {
    double a = 0.0, b = 0.0;
    for (int i = threadIdx.x; i < GRID; i += TPB) {
        a += part_sf[i];
        b += part_su[i];
    }
    b += fix_delta[threadIdx.x];      // TPB == KK == 256
    __shared__ double sred[8];
    __shared__ float sscale;
    #pragma unroll
    for (int off = 32; off > 0; off >>= 1) {
        a += __shfl_down(a, off);
        b += __shfl_down(b, off);
    }
    if ((threadIdx.x & 63) == 0) {
        sred[(threadIdx.x >> 6) * 2 + 0] = a;
        sred[(threadIdx.x >> 6) * 2 + 1] = b;
    }
    __syncthreads();
    if (threadIdx.x == 0) {
        const double ta = sred[0] + sred[2] + sred[4] + sred[6];
        const double tb = sred[1] + sred[3] + sred[5] + sred[7];
        const float s = (tb > 0.0) ? (float)sqrt(ta / tb) : 1.0f;
        sscale = s;
        if (blockIdx.x == 0) *scale_out = s;
    }
    __syncthreads();
    const float scale = sscale;

    const int tid = blockIdx.x * TPB + threadIdx.x;
    float4* __restrict__ O = (float4*)out;
    #pragma unroll
    for (int u = 0; u < ITER / 4; ++u) {
        const int i0 = tid + (4 * u + 0) * STRIDE;
        const int i1 = tid + (4 * u + 1) * STRIDE;
        const int i2 = tid + (4 * u + 2) * STRIDE;
        const int i3 = tid + (4 * u + 3) * STRIDE;
        float4 v0 = O[i0], v1 = O[i1], v2 = O[i2], v3 = O[i3];
        v0.x *= scale; v0.y *= scale; v0.z *= scale; v0.w *= scale;
        v1.x *= scale; v1.y *= scale; v1.z *= scale; v1.w *= scale;
        v2.x *= scale; v2.y *= scale; v2.z *= scale; v2.w *= scale;
        v3.x *= scale; v3.y *= scale; v3.z *= scale; v3.w *= scale;
        O[i0] = v0; O[i1] = v1; O[i2] = v2; O[i3] = v3;
    }
}

// K5: apply sparse corrections, scaled.
__global__ void ecli_apply(const int* __restrict__ list_idx,
                           const float* __restrict__ list_fu,
                           const float* __restrict__ scale_ptr,
                           float* __restrict__ out) {
    const int tid = blockIdx.x * blockDim.x + threadIdx.x;
    if (tid >= MAXTOUCH) return;
    const int idx = list_idx[tid];
    if (idx < 0) return;
    out[idx] = list_fu[tid] * (*scale_ptr);
}

extern "C" void kernel_launch(void* const* d_in, const int* in_sizes, int n_in,
                              void* d_out, int out_size, void* d_ws, size_t ws_size,
                              hipStream_t stream) {
    const float* field    = (const float*)d_in[0];
    const float* signal   = (const float*)d_in[1];
    const int*   pos      = (const int*)d_in[2];
    const float* strength = (const float*)d_in[3];
    const float* infl     = (const float*)d_in[4];
    const float* gratio   = (const float*)d_in[5];
    const float* lratio   = (const float*)d_in[6];
    float* out = (float*)d_out;

    char* ws = (char*)d_ws;
    double* fix_delta = (double*)(ws + FIX_OFF);
    double* part_sf   = (double*)(ws + PSF_OFF);
    double* part_su   = (double*)(ws + PSU_OFF);
    float*  scale_ptr = (float*)(ws + SCALE_OFF);
    int*    list_idx  = (int*)(ws + LIDX_OFF);
    float*  list_fu   = (float*)(ws + LFU_OFF);

    ecli_clear  <<<KK, 448, 0, stream>>>(pos, out);
    ecli_scatter<<<KK, 448, 0, stream>>>(pos, strength, lratio, out);
    ecli_fixup  <<<KK, 448, 0, stream>>>(pos, field, signal, gratio, infl,
                                         out, list_idx, list_fu, fix_delta);
    ecli_blend  <<<GRID, TPB, 0, stream>>>(field, signal, gratio, infl,
                                           out, part_sf, part_su);
    ecli_scale  <<<GRID, TPB, 0, stream>>>(out, part_sf, part_su,
                                           fix_delta, scale_ptr);
    ecli_apply  <<<(MAXTOUCH + 255) / 256, 256, 0, stream>>>(list_idx, list_fu,
                                                             scale_ptr, out);
}